// Round 18
// baseline (235.150 us; speedup 1.0000x reference)
//
#include <hip/hip_runtime.h>
#include <cstdint>

#define BB 4
#define NN 2048
#define KK 32
#define CC 128
#define C0 128
#define C2 256
#define CIN0 259
#define RW 160                 // pre-transposed row width (128 feat | 3 pos | 29 zero)
#define EPSF 1e-5f
#define SLOPE 0.01f

// ---- ws layout (float offsets unless noted) ----
#define PAR0 0
#define PAR1 256
#define PAR2 512                          // -> 1024
#define R1OFF 1024                        // 64x512 -> 33792
#define MAXOFF 33792                      // 8192x256
#define MINOFF (MAXOFF + 2097152)
#define PART   (MINOFF + 2097152)         // A: 4096 rows p256; B: 8192 rows p256; C: 2048 rows p512
#define Y0_USH ((PART + 2097152) * 2)     // ushort offset; 8192x4096 ush (64MB) y0 then y1
#define T2_USH (Y0_USH + 33554432)
#define T1_USH (T2_USH + BB*NN*RW)
#define WP_USH (T1_USH + BB*NN*RW)        // packed W: 176*512 ush

// packed-W frags: L0: 8 mt x 10 ck = 80; L1: 8x4=32; L2(transposed 32x32): 8 tiles x 8 kc = 64
#define NFRAG0 80
#define NFRAG1 32
#define NFRAG2 64

typedef float floatx4 __attribute__((ext_vector_type(4)));
typedef float floatx16 __attribute__((ext_vector_type(16)));
typedef short shortx8 __attribute__((ext_vector_type(8)));
typedef short shortx4 __attribute__((ext_vector_type(4)));

#define MFMA16(A,B,C) __builtin_amdgcn_mfma_f32_16x16x32_bf16((A),(B),(C),0,0,0)
#define MFMA32(A,B,C) __builtin_amdgcn_mfma_f32_32x32x16_bf16((A),(B),(C),0,0,0)

__device__ __forceinline__ ushort f2bf(float f) {
    union { float f; uint u; } v; v.f = f;
    uint r = (v.u + 0x7fffu + ((v.u >> 16) & 1u)) >> 16;
    return (ushort)r;
}

// C-frag y layout: element (k, ch) at ush offset within a point's 4096-ush row:
// frag = (ch>>4)*2 + (k>>4); lane' = ((ch>>2)&3)*16 + (k&15); elem = ch&3
__device__ __forceinline__ int yoff(int k, int ch) {
    return (((ch >> 4) * 2 + (k >> 4)) << 8) + (((((ch >> 2) & 3) << 4) + (k & 15)) << 2) + (ch & 3);
}

// BN(affine)+lrelu on a raw bf16 shortx8 fragment -> bf16 shortx8 (channels chb..chb+7)
__device__ __forceinline__ shortx8 bn_frag(shortx8 raw, const float* __restrict__ par, int chb) {
    floatx4 scA = *(const floatx4*)&par[chb];
    floatx4 scB = *(const floatx4*)&par[chb + 4];
    floatx4 shA = *(const floatx4*)&par[chb + 128];
    floatx4 shB = *(const floatx4*)&par[chb + 132];
    float sc[8] = {scA[0], scA[1], scA[2], scA[3], scB[0], scB[1], scB[2], scB[3]};
    float sh[8] = {shA[0], shA[1], shA[2], shA[3], shB[0], shB[1], shB[2], shB[3]};
    shortx8 out;
#pragma unroll
    for (int i = 0; i < 8; i++) {
        union { uint u; float f; } c;
        c.u = ((uint)(ushort)raw[i]) << 16;
        float z = fmaf(c.f, sc[i], sh[i]);
        z = fmaxf(z, SLOPE * z);
        out[i] = (short)f2bf(z);
    }
    return out;
}

// fused prep: blocks 0-255 transpose (f2,pos2,+1)->T2, 256-511 (f1,pos1,-1)->T1, 512+ pack W
__global__ __launch_bounds__(256) void prep(
    const float* __restrict__ f2, const float* __restrict__ pos2,
    const float* __restrict__ f1, const float* __restrict__ pos1,
    const float* __restrict__ W0, const float* __restrict__ W1,
    const float* __restrict__ W2,
    ushort* __restrict__ T2p, ushort* __restrict__ T1p, short* __restrict__ wp0)
{
    __shared__ __align__(16) ushort Ts[32][168];
    int bid = blockIdx.x;
    int t = threadIdx.x;
    if (bid < 512) {
        const float* feat = (bid < 256) ? f2 : f1;
        const float* pos  = (bid < 256) ? pos2 : pos1;
        float sign        = (bid < 256) ? 1.0f : -1.0f;
        ushort* dst       = (bid < 256) ? T2p : T1p;
        int blk = bid & 255;
        int b = blk >> 6, n0 = (blk & 63) * 32;
#pragma unroll
        for (int i = 0; i < 16; i++) {
            int c = i * 8 + (t >> 5);
            Ts[t & 31][c] = f2bf(feat[((size_t)b * CC + c) * NN + n0 + (t & 31)]);
        }
        if (t < 96) {
            int c = t >> 5, k = t & 31;
            Ts[k][128 + c] = f2bf(sign * pos[((size_t)b * 3 + c) * NN + n0 + k]);
        }
        if (t < 32) {
            for (int c = 131; c < RW; c++) Ts[t][c] = 0;
        }
        __syncthreads();
        int n = t >> 3, q = t & 7;
        ushort* drow = dst + ((size_t)b * NN + n0 + n) * RW;
        *(uint4*)&drow[q * 16]     = *(const uint4*)&Ts[n][q * 16];
        *(uint4*)&drow[q * 16 + 8] = *(const uint4*)&Ts[n][q * 16 + 8];
        if (q < 4) *(uint4*)&drow[128 + q * 8] = *(const uint4*)&Ts[n][128 + q * 8];
    } else {
        int tid = (bid - 512) * 256 + t;           // 44*256 = 11264 = 176*64
        int fid = tid >> 6, lane = tid & 63, g = (lane >> 4) & 3, lcol = lane & 15;
        short* wp1 = wp0 + NFRAG0 * 512;
        short* wp2 = wp1 + NFRAG1 * 512;
        ushort v[8];
        short* dst;
        if (fid < NFRAG0) {
            int mt = fid / 10, ck = fid % 10, o = mt * 16 + lcol;
            const float* wrow = W0 + (size_t)o * CIN0;
            int gather = (ck < 5);
            int cbase = (gather ? ck : ck - 5) * 32 + g * 8;
#pragma unroll
            for (int i = 0; i < 8; i++) {
                int c = cbase + i;
                float x;
                if (c < 128)      x = gather ? wrow[3 + c] : wrow[131 + c];
                else if (c < 131) x = wrow[c - 128];
                else              x = 0.f;
                v[i] = f2bf(x);
            }
            dst = wp0 + ((size_t)fid * 64 + lane) * 8;
        } else if (fid < NFRAG0 + NFRAG1) {
            int f = fid - NFRAG0, mt = f / 4, ck = f % 4, o = mt * 16 + lcol;
#pragma unroll
            for (int i = 0; i < 8; i++) v[i] = f2bf(W1[(size_t)o * C0 + ck * 32 + g * 8 + i]);
            dst = wp1 + ((size_t)f * 64 + lane) * 8;
        } else {
            // W2 packed for transposed 32x32x16 MFMA (B-frag of W2^T == A-frag of W2):
            // frag f = tile*8+kc: lane l elem i -> W2[tile*32 + (l&31)][kc*16 + (l>>5)*8 + i]
            int f = fid - NFRAG0 - NFRAG1;
            int tile = f >> 3, kc = f & 7;
            int o = tile * 32 + (lane & 31);
            int cb = kc * 16 + (lane >> 5) * 8;
#pragma unroll
            for (int i = 0; i < 8; i++) v[i] = f2bf(W2[(size_t)o * C0 + cb + i]);
            dst = wp2 + ((size_t)f * 64 + lane) * 8;
        }
#pragma unroll
        for (int i = 0; i < 8; i++) dst[i] = (short)v[i];
    }
}

// per-wave 128-ch stats row via shfl_xor (proven), pitch 256: [sum128|sq128]
__device__ __forceinline__ void stats_row256(const floatx4 (&acc)[8][2], int g, int lcol,
                                             int pid, float* __restrict__ ws) {
#pragma unroll
    for (int m = 0; m < 8; m++) {
        floatx4 s, q;
#pragma unroll
        for (int r = 0; r < 4; r++) {
            float a0 = acc[m][0][r], a1 = acc[m][1][r];
            float ss = a0 + a1, qq = a0 * a0 + a1 * a1;
#pragma unroll
            for (int d = 1; d < 16; d <<= 1) { ss += __shfl_xor(ss, d); qq += __shfl_xor(qq, d); }
            s[r] = ss; q[r] = qq;
        }
        if (lcol == 0) {
            int ch = m * 16 + g * 4;
            *(floatx4*)&ws[PART + (size_t)pid * 256 + ch] = s;
            *(floatx4*)&ws[PART + (size_t)pid * 256 + 128 + ch] = q;
        }
    }
}

// ---- pass A: block = 2 points, 4 waves split M (acc 32 VGPR -> target <=64 total
// for 8 waves/SIMD occupancy; launch_bounds(256,4) = no allocator clamp pressure).
// L0 once, store raw y0 bf16 in C-frag layout (coalesced); stats over 2 points
// -> one partial row per block (4096 rows, pitch 256).
__global__ __launch_bounds__(256, 4) void pass_A(
    const ushort* __restrict__ T2x, const ushort* __restrict__ T1x,
    const int* __restrict__ idxg, const short* __restrict__ wp0,
    float* __restrict__ ws, ushort* __restrict__ y0)
{
    const int t = threadIdx.x;
    const int wave = t >> 6, lane = t & 63, g = lane >> 4, lcol = lane & 15;
    const int bid = blockIdx.x, pid0 = bid * 2;
    const int b = pid0 >> 11;
    const shortx8* wf0 = (const shortx8*)wp0;

    const ushort* r0[2]; const ushort* r1[2]; const ushort* fr[2];
#pragma unroll
    for (int p = 0; p < 2; p++) {
        int pid = pid0 + p;
        int n = pid & (NN - 1);
        int j0 = idxg[pid * KK + lcol];
        int j1 = idxg[pid * KK + 16 + lcol];
        r0[p] = T2x + ((size_t)(b * NN + j0)) * RW;
        r1[p] = T2x + ((size_t)(b * NN + j1)) * RW;
        fr[p] = T1x + ((size_t)(b * NN + n)) * RW;
    }

    floatx4 acc[2][2][2] = {};      // [p][m][nt]  (32 VGPRs)
#pragma unroll
    for (int ck = 0; ck < 5; ck++) {           // gather chunks
        shortx8 B0[2], B1[2];
#pragma unroll
        for (int p = 0; p < 2; p++) {
            B0[p] = *(const shortx8*)(r0[p] + ck * 32 + g * 8);
            B1[p] = *(const shortx8*)(r1[p] + ck * 32 + g * 8);
        }
#pragma unroll
        for (int m = 0; m < 2; m++) {
            shortx8 A = wf0[((wave * 2 + m) * 10 + ck) * 64 + lane];
#pragma unroll
            for (int p = 0; p < 2; p++) {
                acc[p][m][0] = MFMA16(A, B0[p], acc[p][m][0]);
                acc[p][m][1] = MFMA16(A, B1[p], acc[p][m][1]);
            }
        }
    }
#pragma unroll
    for (int ck = 0; ck < 5; ck++) {           // broadcast chunks (f1 | -pos1)
        shortx8 F[2];
#pragma unroll
        for (int p = 0; p < 2; p++)
            F[p] = *(const shortx8*)(fr[p] + ck * 32 + g * 8);
#pragma unroll
        for (int m = 0; m < 2; m++) {
            shortx8 A = wf0[((wave * 2 + m) * 10 + 5 + ck) * 64 + lane];
#pragma unroll
            for (int p = 0; p < 2; p++) {
                acc[p][m][0] = MFMA16(A, F[p], acc[p][m][0]);
                acc[p][m][1] = MFMA16(A, F[p], acc[p][m][1]);
            }
        }
    }

    // store y0 in C-frag layout: addr = base + lane*4 -> fully coalesced
#pragma unroll
    for (int p = 0; p < 2; p++) {
        ushort* yr = y0 + (size_t)(pid0 + p) * 4096;
#pragma unroll
        for (int nt = 0; nt < 2; nt++) {
            int k = nt * 16 + lcol;
#pragma unroll
            for (int m = 0; m < 2; m++) {
                int ch = (wave * 2 + m) * 16 + g * 4;
                shortx4 cv;
                cv[0] = (short)f2bf(acc[p][m][nt][0]);
                cv[1] = (short)f2bf(acc[p][m][nt][1]);
                cv[2] = (short)f2bf(acc[p][m][nt][2]);
                cv[3] = (short)f2bf(acc[p][m][nt][3]);
                *(shortx4*)(yr + yoff(k, ch)) = cv;
            }
        }
    }

    // stats: accumulate over the 2 points lane-locally, one row per block
#pragma unroll
    for (int m = 0; m < 2; m++) {
        floatx4 s = {}, q = {};
#pragma unroll
        for (int p = 0; p < 2; p++)
#pragma unroll
            for (int r = 0; r < 4; r++) {
                float a0 = acc[p][m][0][r], a1 = acc[p][m][1][r];
                s[r] += a0 + a1; q[r] += a0 * a0 + a1 * a1;
            }
#pragma unroll
        for (int r = 0; r < 4; r++) {
            float ss = s[r], qq = q[r];
#pragma unroll
            for (int d = 1; d < 16; d <<= 1) { ss += __shfl_xor(ss, d); qq += __shfl_xor(qq, d); }
            s[r] = ss; q[r] = qq;
        }
        if (lcol == 0) {
            int ch = (wave * 2 + m) * 16 + g * 4;
            *(floatx4*)&ws[PART + (size_t)bid * 256 + ch] = s;
            *(floatx4*)&ws[PART + (size_t)bid * 256 + 128 + ch] = q;
        }
    }
}

// load a B/A-side shortx8 (8 consecutive channels ch0..ch0+7 at row k) from C-frag y
__device__ __forceinline__ shortx8 yload8(const ushort* __restrict__ yr, int k, int ch0) {
    union { shortx4 q[2]; shortx8 v; } u;
    u.q[0] = *(const shortx4*)(yr + yoff(k, ch0));
    u.q[1] = *(const shortx4*)(yr + yoff(k, ch0 + 4));
    return u.v;
}

// ---- pass B: y0 -> BN0(in-reg) -> L1 -> stats1; overwrite y0 rows with raw y1 ----
__global__ __launch_bounds__(256, 4) void pass_B(ushort* __restrict__ y01,
                                                 const short* __restrict__ wp0,
                                                 float* __restrict__ ws)
{
    const int t = threadIdx.x;
    const int wave = t >> 6, lane = t & 63, g = lane >> 4, lcol = lane & 15;
    const int pid = blockIdx.x * 4 + wave;
    const shortx8* wf1 = (const shortx8*)wp0 + NFRAG0 * 64;
    ushort* yr = y01 + (size_t)pid * 4096;

    floatx4 acc1[8][2] = {};
#pragma unroll
    for (int ck = 0; ck < 4; ck++) {
        int chb = ck * 32 + g * 8;
        shortx8 B0 = bn_frag(yload8(yr, lcol, chb), ws + PAR0, chb);
        shortx8 B1 = bn_frag(yload8(yr, lcol + 16, chb), ws + PAR0, chb);
#pragma unroll
        for (int mt = 0; mt < 8; mt++) {
            shortx8 A = wf1[(mt * 4 + ck) * 64 + lane];
            acc1[mt][0] = MFMA16(A, B0, acc1[mt][0]);
            acc1[mt][1] = MFMA16(A, B1, acc1[mt][1]);
        }
    }
    stats_row256(acc1, g, lcol, pid, ws);
    // All y0 reads complete above. Fence pins compiler ordering; stores are
    // short-typed to share the loads' TBAA class.
    asm volatile("" ::: "memory");
    // overwrite with raw y1 (same C-frag layout, coalesced)
#pragma unroll
    for (int nt = 0; nt < 2; nt++) {
        int k = nt * 16 + lcol;
#pragma unroll
        for (int mt = 0; mt < 8; mt++) {
            int ch = mt * 16 + g * 4;
            shortx4 cv;
            cv[0] = (short)f2bf(acc1[mt][nt][0]);
            cv[1] = (short)f2bf(acc1[mt][nt][1]);
            cv[2] = (short)f2bf(acc1[mt][nt][2]);
            cv[3] = (short)f2bf(acc1[mt][nt][3]);
            *(shortx4*)(yr + yoff(k, ch)) = cv;
        }
    }
}

// ---- pass C (transposed): y2^T = h1^T · W2^T via mfma_f32_32x32x16_bf16.
// D[k][ch]: k in regs, ch = tile*32 + (lane&31). k-reductions lane-local + one shfl(32).
__global__ __launch_bounds__(256, 4) void pass_C(const ushort* __restrict__ y01,
                                                 const short* __restrict__ wp0,
                                                 float* __restrict__ ws)
{
    __shared__ float Sacc[4][512];
    const int t = threadIdx.x;
    const int wave = t >> 6, lane = t & 63;
    const int l31 = lane & 31, lh = lane >> 5;
    const int bid = blockIdx.x;
    const int pid = bid * 4 + wave;
    const shortx8* wf2 = (const shortx8*)wp0 + (NFRAG0 + NFRAG1) * 64;
    const ushort* yr = y01 + (size_t)pid * 4096;

    // A-side fragments: h1^T[k=l31][c = kc*16 + lh*8 + i], BN1 applied in-register
    shortx8 hA[8];
#pragma unroll
    for (int kc = 0; kc < 8; kc++) {
        int chb = kc * 16 + lh * 8;
        hA[kc] = bn_frag(yload8(yr, l31, chb), ws + PAR1, chb);
    }

#pragma unroll
    for (int tile = 0; tile < 8; tile++) {
        floatx16 acc = {};
#pragma unroll
        for (int kc = 0; kc < 8; kc++)
            acc = MFMA32(hA[kc], wf2[(tile * 8 + kc) * 64 + lane], acc);
        // lane-local k-reduction over 16 regs, then combine with partner lane (^32)
        float s = 0.f, q = 0.f, mx = -1e30f, mn = 1e30f;
#pragma unroll
        for (int r = 0; r < 16; r++) {
            float v = acc[r];
            s += v; q += v * v;
            mx = fmaxf(mx, v); mn = fminf(mn, v);
        }
        s += __shfl_xor(s, 32);
        q += __shfl_xor(q, 32);
        mx = fmaxf(mx, __shfl_xor(mx, 32));
        mn = fminf(mn, __shfl_xor(mn, 32));
        if (lane < 32) {
            int ch = tile * 32 + l31;
            ws[MAXOFF + (size_t)pid * C2 + ch] = mx;
            ws[MINOFF + (size_t)pid * C2 + ch] = mn;
            Sacc[wave][ch] = s;
            Sacc[wave][256 + ch] = q;
        }
    }
    __syncthreads();
    // combine 4 waves' stats -> one row per block (2048 rows, pitch 512)
    float a = Sacc[0][t] + Sacc[1][t] + Sacc[2][t] + Sacc[3][t];
    float bq = Sacc[0][t + 256] + Sacc[1][t + 256] + Sacc[2][t + 256] + Sacc[3][t + 256];
    ws[PART + (size_t)bid * 512 + t] = a;
    ws[PART + (size_t)bid * 512 + 256 + t] = bq;
}

// level-1 reduction of partial rows -> 64 rows at R1OFF (pitch 512)
__global__ __launch_bounds__(256) void reduce1(float* __restrict__ ws, int srcoff,
                                               int rpb, int pitch, int ncol) {
    int j = blockIdx.x, t = threadIdx.x;
    const float* base = ws + srcoff + (size_t)j * rpb * pitch;
    float a0 = 0.f, a1 = 0.f;
    for (int i = 0; i < rpb; i++) {
        a0 += base[(size_t)i * pitch + t];
        if (ncol > 256) a1 += base[(size_t)i * pitch + 256 + t];
    }
    ws[R1OFF + (size_t)j * 512 + t] = a0;
    if (ncol > 256) ws[R1OFF + (size_t)j * 512 + 256 + t] = a1;
}

__global__ void finalize(const float* __restrict__ g, const float* __restrict__ bparm,
                         float* __restrict__ ws, int CL, int paroff) {
    int ch = threadIdx.x;
    if (ch >= CL) return;
    float s = 0.f, s2 = 0.f;
    for (int j = 0; j < 64; j++) {
        s  += ws[R1OFF + (size_t)j * 512 + ch];
        s2 += ws[R1OFF + (size_t)j * 512 + CL + ch];
    }
    const float inv = 1.0f / ((float)BB * NN * KK);
    float mean = s * inv, var = s2 * inv - mean * mean;
    float sc = g[ch] * rsqrtf(var + EPSF);
    ws[paroff + ch] = sc;
    ws[paroff + CL + ch] = bparm[ch] - mean * sc;
}

// out = lrelu(scale*(scale>=0?max:min)+shift), transposed through LDS
__global__ __launch_bounds__(256) void out_kernel(const float* __restrict__ ws,
                                                  float* __restrict__ out) {
    __shared__ float T[32][261];
    int blk = blockIdx.x;                  // 256 blocks
    int b = blk >> 6, n0 = (blk & 63) * 32;
    int t = threadIdx.x;
    float s = ws[PAR2 + t], sh = ws[PAR2 + C2 + t];
    const float* Mx = ws + MAXOFF;
    const float* Mn = ws + MINOFF;
    for (int r = 0; r < 32; r++) {
        size_t base = ((size_t)(b * NN + n0 + r)) * C2 + t;
        float v = (s >= 0.f) ? Mx[base] : Mn[base];
        float z = fmaf(v, s, sh);
        T[r][t] = z >= 0.f ? z : SLOPE * z;
    }
    __syncthreads();
    float* o2 = out + BB * 3 * NN;
    int c = t & 31, og = t >> 5;
    for (int ss = 0; ss < 32; ss++) {
        int o = og * 32 + ss;
        o2[((size_t)(b * C2 + o)) * NN + n0 + c] = T[c][o];
    }
}

extern "C" void kernel_launch(void* const* d_in, const int* in_sizes, int n_in,
                              void* d_out, int out_size, void* d_ws, size_t ws_size,
                              hipStream_t stream) {
    const float* pos1 = (const float*)d_in[0];
    const float* pos2 = (const float*)d_in[1];
    const float* f1   = (const float*)d_in[2];
    const float* f2   = (const float*)d_in[3];
    const int*   idx  = (const int*)d_in[4];
    const float* W0 = (const float*)d_in[5];
    const float* g0 = (const float*)d_in[6];
    const float* b0 = (const float*)d_in[7];
    const float* W1 = (const float*)d_in[8];
    const float* g1 = (const float*)d_in[9];
    const float* b1 = (const float*)d_in[10];
    const float* W2 = (const float*)d_in[11];
    const float* g2 = (const float*)d_in[12];
    const float* b2 = (const float*)d_in[13];
    float* ws  = (float*)d_ws;
    float* out = (float*)d_out;
    ushort* wsu = (ushort*)d_ws;
    ushort* y0p = wsu + Y0_USH;
    ushort* T2p = wsu + T2_USH;
    ushort* T1p = wsu + T1_USH;
    short* wp0  = (short*)(wsu + WP_USH);

    // output 0: pos1 passthrough
    hipMemcpyAsync(d_out, d_in[0], (size_t)BB * 3 * NN * sizeof(float),
                   hipMemcpyDeviceToDevice, stream);

    prep<<<512 + 44, 256, 0, stream>>>(f2, pos2, f1, pos1, W0, W1, W2, T2p, T1p, wp0);

    pass_A<<<BB * NN / 2, 256, 0, stream>>>(T2p, T1p, idx, wp0, ws, y0p);
    reduce1<<<64, 256, 0, stream>>>(ws, PART, 64, 256, 256);
    finalize<<<1, 256, 0, stream>>>(g0, b0, ws, C0, PAR0);

    pass_B<<<BB * NN / 4, 256, 0, stream>>>(y0p, wp0, ws);
    reduce1<<<64, 256, 0, stream>>>(ws, PART, 128, 256, 256);
    finalize<<<1, 256, 0, stream>>>(g1, b1, ws, C0, PAR1);

    pass_C<<<BB * NN / 4, 256, 0, stream>>>(y0p, wp0, ws);
    reduce1<<<64, 256, 0, stream>>>(ws, PART, 32, 512, 512);
    finalize<<<1, 256, 0, stream>>>(g2, b2, ws, C2, PAR2);

    out_kernel<<<BB * (NN / 32), 256, 0, stream>>>(ws, out);
}

// Round 19
// 227.281 us; speedup vs baseline: 1.0346x; 1.0346x over previous
//
#include <hip/hip_runtime.h>
#include <cstdint>

#define BB 4
#define NN 2048
#define KK 32
#define CC 128
#define C0 128
#define C2 256
#define CIN0 259
#define RW 160                 // pre-transposed row width (128 feat | 3 pos | 29 zero)
#define EPSF 1e-5f
#define SLOPE 0.01f

// ---- ws layout (float offsets unless noted) ----
#define PAR0 0
#define PAR1 256
#define PAR2 512                          // -> 1024
#define R1OFF 1024                        // 64x512 -> 33792
#define MAXOFF 33792                      // 8192x256
#define MINOFF (MAXOFF + 2097152)
#define PART   (MINOFF + 2097152)         // A/C: 2048 rows; B: 8192 rows
#define Y0_USH ((PART + 2097152) * 2)     // ushort offset; 8192x4096 ush (64MB) y0 then y1
#define T2_USH (Y0_USH + 33554432)
#define T1_USH (T2_USH + BB*NN*RW)
#define WP_USH (T1_USH + BB*NN*RW)        // packed W: 176*512 ush

// packed-W frags: L0: 8 mt x 10 ck = 80; L1: 8x4=32; L2(transposed 32x32): 8 tiles x 8 kc = 64
#define NFRAG0 80
#define NFRAG1 32
#define NFRAG2 64

typedef float floatx4 __attribute__((ext_vector_type(4)));
typedef float floatx16 __attribute__((ext_vector_type(16)));
typedef short shortx8 __attribute__((ext_vector_type(8)));
typedef short shortx4 __attribute__((ext_vector_type(4)));

#define MFMA16(A,B,C) __builtin_amdgcn_mfma_f32_16x16x32_bf16((A),(B),(C),0,0,0)
#define MFMA32(A,B,C) __builtin_amdgcn_mfma_f32_32x32x16_bf16((A),(B),(C),0,0,0)

__device__ __forceinline__ ushort f2bf(float f) {
    union { float f; uint u; } v; v.f = f;
    uint r = (v.u + 0x7fffu + ((v.u >> 16) & 1u)) >> 16;
    return (ushort)r;
}

// C-frag y layout: element (k, ch) at ush offset within a point's 4096-ush row:
// frag = (ch>>4)*2 + (k>>4); lane' = ((ch>>2)&3)*16 + (k&15); elem = ch&3
__device__ __forceinline__ int yoff(int k, int ch) {
    return (((ch >> 4) * 2 + (k >> 4)) << 8) + (((((ch >> 2) & 3) << 4) + (k & 15)) << 2) + (ch & 3);
}

// BN(affine)+lrelu on a raw bf16 shortx8 fragment -> bf16 shortx8 (channels chb..chb+7)
__device__ __forceinline__ shortx8 bn_frag(shortx8 raw, const float* __restrict__ par, int chb) {
    floatx4 scA = *(const floatx4*)&par[chb];
    floatx4 scB = *(const floatx4*)&par[chb + 4];
    floatx4 shA = *(const floatx4*)&par[chb + 128];
    floatx4 shB = *(const floatx4*)&par[chb + 132];
    float sc[8] = {scA[0], scA[1], scA[2], scA[3], scB[0], scB[1], scB[2], scB[3]};
    float sh[8] = {shA[0], shA[1], shA[2], shA[3], shB[0], shB[1], shB[2], shB[3]};
    shortx8 out;
#pragma unroll
    for (int i = 0; i < 8; i++) {
        union { uint u; float f; } c;
        c.u = ((uint)(ushort)raw[i]) << 16;
        float z = fmaf(c.f, sc[i], sh[i]);
        z = fmaxf(z, SLOPE * z);
        out[i] = (short)f2bf(z);
    }
    return out;
}

// fused prep: blocks 0-255 transpose (f2,pos2,+1)->T2, 256-511 (f1,pos1,-1)->T1, 512+ pack W
__global__ __launch_bounds__(256) void prep(
    const float* __restrict__ f2, const float* __restrict__ pos2,
    const float* __restrict__ f1, const float* __restrict__ pos1,
    const float* __restrict__ W0, const float* __restrict__ W1,
    const float* __restrict__ W2,
    ushort* __restrict__ T2p, ushort* __restrict__ T1p, short* __restrict__ wp0)
{
    __shared__ __align__(16) ushort Ts[32][168];
    int bid = blockIdx.x;
    int t = threadIdx.x;
    if (bid < 512) {
        const float* feat = (bid < 256) ? f2 : f1;
        const float* pos  = (bid < 256) ? pos2 : pos1;
        float sign        = (bid < 256) ? 1.0f : -1.0f;
        ushort* dst       = (bid < 256) ? T2p : T1p;
        int blk = bid & 255;
        int b = blk >> 6, n0 = (blk & 63) * 32;
#pragma unroll
        for (int i = 0; i < 16; i++) {
            int c = i * 8 + (t >> 5);
            Ts[t & 31][c] = f2bf(feat[((size_t)b * CC + c) * NN + n0 + (t & 31)]);
        }
        if (t < 96) {
            int c = t >> 5, k = t & 31;
            Ts[k][128 + c] = f2bf(sign * pos[((size_t)b * 3 + c) * NN + n0 + k]);
        }
        if (t < 32) {
            for (int c = 131; c < RW; c++) Ts[t][c] = 0;
        }
        __syncthreads();
        int n = t >> 3, q = t & 7;
        ushort* drow = dst + ((size_t)b * NN + n0 + n) * RW;
        *(uint4*)&drow[q * 16]     = *(const uint4*)&Ts[n][q * 16];
        *(uint4*)&drow[q * 16 + 8] = *(const uint4*)&Ts[n][q * 16 + 8];
        if (q < 4) *(uint4*)&drow[128 + q * 8] = *(const uint4*)&Ts[n][128 + q * 8];
    } else {
        int tid = (bid - 512) * 256 + t;           // 44*256 = 11264 = 176*64
        int fid = tid >> 6, lane = tid & 63, g = (lane >> 4) & 3, lcol = lane & 15;
        short* wp1 = wp0 + NFRAG0 * 512;
        short* wp2 = wp1 + NFRAG1 * 512;
        ushort v[8];
        short* dst;
        if (fid < NFRAG0) {
            int mt = fid / 10, ck = fid % 10, o = mt * 16 + lcol;
            const float* wrow = W0 + (size_t)o * CIN0;
            int gather = (ck < 5);
            int cbase = (gather ? ck : ck - 5) * 32 + g * 8;
#pragma unroll
            for (int i = 0; i < 8; i++) {
                int c = cbase + i;
                float x;
                if (c < 128)      x = gather ? wrow[3 + c] : wrow[131 + c];
                else if (c < 131) x = wrow[c - 128];
                else              x = 0.f;
                v[i] = f2bf(x);
            }
            dst = wp0 + ((size_t)fid * 64 + lane) * 8;
        } else if (fid < NFRAG0 + NFRAG1) {
            int f = fid - NFRAG0, mt = f / 4, ck = f % 4, o = mt * 16 + lcol;
#pragma unroll
            for (int i = 0; i < 8; i++) v[i] = f2bf(W1[(size_t)o * C0 + ck * 32 + g * 8 + i]);
            dst = wp1 + ((size_t)f * 64 + lane) * 8;
        } else {
            // W2 packed for transposed 32x32x16 MFMA (B-frag of W2^T == A-frag of W2):
            // frag f = tile*8+kc: lane l elem i -> W2[tile*32 + (l&31)][kc*16 + (l>>5)*8 + i]
            int f = fid - NFRAG0 - NFRAG1;
            int tile = f >> 3, kc = f & 7;
            int o = tile * 32 + (lane & 31);
            int cb = kc * 16 + (lane >> 5) * 8;
#pragma unroll
            for (int i = 0; i < 8; i++) v[i] = f2bf(W2[(size_t)o * C0 + cb + i]);
            dst = wp2 + ((size_t)f * 64 + lane) * 8;
        }
#pragma unroll
        for (int i = 0; i < 8; i++) dst[i] = (short)v[i];
    }
}

// per-wave 128-ch stats row via shfl_xor (proven), pitch 256: [sum128|sq128]
__device__ __forceinline__ void stats_row256(const floatx4 (&acc)[8][2], int g, int lcol,
                                             int pid, float* __restrict__ ws) {
#pragma unroll
    for (int m = 0; m < 8; m++) {
        floatx4 s, q;
#pragma unroll
        for (int r = 0; r < 4; r++) {
            float a0 = acc[m][0][r], a1 = acc[m][1][r];
            float ss = a0 + a1, qq = a0 * a0 + a1 * a1;
#pragma unroll
            for (int d = 1; d < 16; d <<= 1) { ss += __shfl_xor(ss, d); qq += __shfl_xor(qq, d); }
            s[r] = ss; q[r] = qq;
        }
        if (lcol == 0) {
            int ch = m * 16 + g * 4;
            *(floatx4*)&ws[PART + (size_t)pid * 256 + ch] = s;
            *(floatx4*)&ws[PART + (size_t)pid * 256 + 128 + ch] = q;
        }
    }
}

// ---- pass A: block = 4 points, 4 waves split M (r13-proven: launch_bounds(256,3),
// 72 VGPR, no spill). L0 once, store raw y0 bf16 in C-frag layout (coalesced);
// stats over 4 points -> one partial row per block.
__global__ __launch_bounds__(256, 3) void pass_A(
    const ushort* __restrict__ T2x, const ushort* __restrict__ T1x,
    const int* __restrict__ idxg, const short* __restrict__ wp0,
    float* __restrict__ ws, ushort* __restrict__ y0)
{
    const int t = threadIdx.x;
    const int wave = t >> 6, lane = t & 63, g = lane >> 4, lcol = lane & 15;
    const int bid = blockIdx.x, pid0 = bid * 4;
    const int b = pid0 >> 11;
    const shortx8* wf0 = (const shortx8*)wp0;

    const ushort* r0[4]; const ushort* r1[4]; const ushort* fr[4];
#pragma unroll
    for (int p = 0; p < 4; p++) {
        int pid = pid0 + p;
        int n = pid & (NN - 1);
        int j0 = idxg[pid * KK + lcol];
        int j1 = idxg[pid * KK + 16 + lcol];
        r0[p] = T2x + ((size_t)(b * NN + j0)) * RW;
        r1[p] = T2x + ((size_t)(b * NN + j1)) * RW;
        fr[p] = T1x + ((size_t)(b * NN + n)) * RW;
    }

    floatx4 acc[4][2][2] = {};      // [p][m][nt]
#pragma unroll
    for (int ck = 0; ck < 5; ck++) {           // gather chunks
        shortx8 B0[4], B1[4];
#pragma unroll
        for (int p = 0; p < 4; p++) {
            B0[p] = *(const shortx8*)(r0[p] + ck * 32 + g * 8);
            B1[p] = *(const shortx8*)(r1[p] + ck * 32 + g * 8);
        }
#pragma unroll
        for (int m = 0; m < 2; m++) {
            shortx8 A = wf0[((wave * 2 + m) * 10 + ck) * 64 + lane];
#pragma unroll
            for (int p = 0; p < 4; p++) {
                acc[p][m][0] = MFMA16(A, B0[p], acc[p][m][0]);
                acc[p][m][1] = MFMA16(A, B1[p], acc[p][m][1]);
            }
        }
    }
#pragma unroll
    for (int ck = 0; ck < 5; ck++) {           // broadcast chunks (f1 | -pos1)
        shortx8 F[4];
#pragma unroll
        for (int p = 0; p < 4; p++)
            F[p] = *(const shortx8*)(fr[p] + ck * 32 + g * 8);
#pragma unroll
        for (int m = 0; m < 2; m++) {
            shortx8 A = wf0[((wave * 2 + m) * 10 + 5 + ck) * 64 + lane];
#pragma unroll
            for (int p = 0; p < 4; p++) {
                acc[p][m][0] = MFMA16(A, F[p], acc[p][m][0]);
                acc[p][m][1] = MFMA16(A, F[p], acc[p][m][1]);
            }
        }
    }

    // store y0 in C-frag layout: addr = base + lane*4 -> fully coalesced
#pragma unroll
    for (int p = 0; p < 4; p++) {
        ushort* yr = y0 + (size_t)(pid0 + p) * 4096;
#pragma unroll
        for (int nt = 0; nt < 2; nt++) {
            int k = nt * 16 + lcol;
#pragma unroll
            for (int m = 0; m < 2; m++) {
                int ch = (wave * 2 + m) * 16 + g * 4;
                shortx4 cv;
                cv[0] = (short)f2bf(acc[p][m][nt][0]);
                cv[1] = (short)f2bf(acc[p][m][nt][1]);
                cv[2] = (short)f2bf(acc[p][m][nt][2]);
                cv[3] = (short)f2bf(acc[p][m][nt][3]);
                *(shortx4*)(yr + yoff(k, ch)) = cv;
            }
        }
    }

    // stats: accumulate over the 4 points lane-locally, one row per block
#pragma unroll
    for (int m = 0; m < 2; m++) {
        floatx4 s = {}, q = {};
#pragma unroll
        for (int p = 0; p < 4; p++)
#pragma unroll
            for (int r = 0; r < 4; r++) {
                float a0 = acc[p][m][0][r], a1 = acc[p][m][1][r];
                s[r] += a0 + a1; q[r] += a0 * a0 + a1 * a1;
            }
#pragma unroll
        for (int r = 0; r < 4; r++) {
            float ss = s[r], qq = q[r];
#pragma unroll
            for (int d = 1; d < 16; d <<= 1) { ss += __shfl_xor(ss, d); qq += __shfl_xor(qq, d); }
            s[r] = ss; q[r] = qq;
        }
        if (lcol == 0) {
            int ch = (wave * 2 + m) * 16 + g * 4;
            *(floatx4*)&ws[PART + (size_t)bid * 256 + ch] = s;
            *(floatx4*)&ws[PART + (size_t)bid * 256 + 128 + ch] = q;
        }
    }
}

// load a B/A-side shortx8 (8 consecutive channels ch0..ch0+7 at row k) from C-frag y
__device__ __forceinline__ shortx8 yload8(const ushort* __restrict__ yr, int k, int ch0) {
    union { shortx4 q[2]; shortx8 v; } u;
    u.q[0] = *(const shortx4*)(yr + yoff(k, ch0));
    u.q[1] = *(const shortx4*)(yr + yoff(k, ch0 + 4));
    return u.v;
}

// ---- pass B: y0 -> BN0(in-reg) -> L1 -> stats1; overwrite y0 rows with raw y1 ----
__global__ __launch_bounds__(256, 4) void pass_B(ushort* __restrict__ y01,
                                                 const short* __restrict__ wp0,
                                                 float* __restrict__ ws)
{
    const int t = threadIdx.x;
    const int wave = t >> 6, lane = t & 63, g = lane >> 4, lcol = lane & 15;
    const int pid = blockIdx.x * 4 + wave;
    const shortx8* wf1 = (const shortx8*)wp0 + NFRAG0 * 64;
    ushort* yr = y01 + (size_t)pid * 4096;

    floatx4 acc1[8][2] = {};
#pragma unroll
    for (int ck = 0; ck < 4; ck++) {
        int chb = ck * 32 + g * 8;
        shortx8 B0 = bn_frag(yload8(yr, lcol, chb), ws + PAR0, chb);
        shortx8 B1 = bn_frag(yload8(yr, lcol + 16, chb), ws + PAR0, chb);
#pragma unroll
        for (int mt = 0; mt < 8; mt++) {
            shortx8 A = wf1[(mt * 4 + ck) * 64 + lane];
            acc1[mt][0] = MFMA16(A, B0, acc1[mt][0]);
            acc1[mt][1] = MFMA16(A, B1, acc1[mt][1]);
        }
    }
    stats_row256(acc1, g, lcol, pid, ws);
    // All y0 reads complete above. Fence pins compiler ordering; stores are
    // short-typed to share the loads' TBAA class.
    asm volatile("" ::: "memory");
    // overwrite with raw y1 (same C-frag layout, coalesced)
#pragma unroll
    for (int nt = 0; nt < 2; nt++) {
        int k = nt * 16 + lcol;
#pragma unroll
        for (int mt = 0; mt < 8; mt++) {
            int ch = mt * 16 + g * 4;
            shortx4 cv;
            cv[0] = (short)f2bf(acc1[mt][nt][0]);
            cv[1] = (short)f2bf(acc1[mt][nt][1]);
            cv[2] = (short)f2bf(acc1[mt][nt][2]);
            cv[3] = (short)f2bf(acc1[mt][nt][3]);
            *(shortx4*)(yr + yoff(k, ch)) = cv;
        }
    }
}

// ---- pass C (transposed): y2^T = h1^T · W2^T via mfma_f32_32x32x16_bf16.
// D[k][ch]: k in regs, ch = tile*32 + (lane&31). k-reductions lane-local + one shfl(32).
__global__ __launch_bounds__(256, 4) void pass_C(const ushort* __restrict__ y01,
                                                 const short* __restrict__ wp0,
                                                 float* __restrict__ ws)
{
    __shared__ float Sacc[4][512];
    const int t = threadIdx.x;
    const int wave = t >> 6, lane = t & 63;
    const int l31 = lane & 31, lh = lane >> 5;
    const int bid = blockIdx.x;
    const int pid = bid * 4 + wave;
    const shortx8* wf2 = (const shortx8*)wp0 + (NFRAG0 + NFRAG1) * 64;
    const ushort* yr = y01 + (size_t)pid * 4096;

    // A-side fragments: h1^T[k=l31][c = kc*16 + lh*8 + i], BN1 applied in-register
    shortx8 hA[8];
#pragma unroll
    for (int kc = 0; kc < 8; kc++) {
        int chb = kc * 16 + lh * 8;
        hA[kc] = bn_frag(yload8(yr, l31, chb), ws + PAR1, chb);
    }

#pragma unroll
    for (int tile = 0; tile < 8; tile++) {
        floatx16 acc = {};
#pragma unroll
        for (int kc = 0; kc < 8; kc++)
            acc = MFMA32(hA[kc], wf2[(tile * 8 + kc) * 64 + lane], acc);
        // lane-local k-reduction over 16 regs, then combine with partner lane (^32)
        float s = 0.f, q = 0.f, mx = -1e30f, mn = 1e30f;
#pragma unroll
        for (int r = 0; r < 16; r++) {
            float v = acc[r];
            s += v; q += v * v;
            mx = fmaxf(mx, v); mn = fminf(mn, v);
        }
        s += __shfl_xor(s, 32);
        q += __shfl_xor(q, 32);
        mx = fmaxf(mx, __shfl_xor(mx, 32));
        mn = fminf(mn, __shfl_xor(mn, 32));
        if (lane < 32) {
            int ch = tile * 32 + l31;
            ws[MAXOFF + (size_t)pid * C2 + ch] = mx;
            ws[MINOFF + (size_t)pid * C2 + ch] = mn;
            Sacc[wave][ch] = s;
            Sacc[wave][256 + ch] = q;
        }
    }
    __syncthreads();
    // combine 4 waves' stats -> one row per block (2048 rows, pitch 512)
    float a = Sacc[0][t] + Sacc[1][t] + Sacc[2][t] + Sacc[3][t];
    float bq = Sacc[0][t + 256] + Sacc[1][t + 256] + Sacc[2][t + 256] + Sacc[3][t + 256];
    ws[PART + (size_t)bid * 512 + t] = a;
    ws[PART + (size_t)bid * 512 + 256 + t] = bq;
}

// level-1 reduction of partial rows -> 64 rows at R1OFF (pitch 512)
__global__ __launch_bounds__(256) void reduce1(float* __restrict__ ws, int srcoff,
                                               int rpb, int pitch, int ncol) {
    int j = blockIdx.x, t = threadIdx.x;
    const float* base = ws + srcoff + (size_t)j * rpb * pitch;
    float a0 = 0.f, a1 = 0.f;
    for (int i = 0; i < rpb; i++) {
        a0 += base[(size_t)i * pitch + t];
        if (ncol > 256) a1 += base[(size_t)i * pitch + 256 + t];
    }
    ws[R1OFF + (size_t)j * 512 + t] = a0;
    if (ncol > 256) ws[R1OFF + (size_t)j * 512 + 256 + t] = a1;
}

__global__ void finalize(const float* __restrict__ g, const float* __restrict__ bparm,
                         float* __restrict__ ws, int CL, int paroff) {
    int ch = threadIdx.x;
    if (ch >= CL) return;
    float s = 0.f, s2 = 0.f;
    for (int j = 0; j < 64; j++) {
        s  += ws[R1OFF + (size_t)j * 512 + ch];
        s2 += ws[R1OFF + (size_t)j * 512 + CL + ch];
    }
    const float inv = 1.0f / ((float)BB * NN * KK);
    float mean = s * inv, var = s2 * inv - mean * mean;
    float sc = g[ch] * rsqrtf(var + EPSF);
    ws[paroff + ch] = sc;
    ws[paroff + CL + ch] = bparm[ch] - mean * sc;
}

// out = lrelu(scale*(scale>=0?max:min)+shift), transposed through LDS
__global__ __launch_bounds__(256) void out_kernel(const float* __restrict__ ws,
                                                  float* __restrict__ out) {
    __shared__ float T[32][261];
    int blk = blockIdx.x;                  // 256 blocks
    int b = blk >> 6, n0 = (blk & 63) * 32;
    int t = threadIdx.x;
    float s = ws[PAR2 + t], sh = ws[PAR2 + C2 + t];
    const float* Mx = ws + MAXOFF;
    const float* Mn = ws + MINOFF;
    for (int r = 0; r < 32; r++) {
        size_t base = ((size_t)(b * NN + n0 + r)) * C2 + t;
        float v = (s >= 0.f) ? Mx[base] : Mn[base];
        float z = fmaf(v, s, sh);
        T[r][t] = z >= 0.f ? z : SLOPE * z;
    }
    __syncthreads();
    float* o2 = out + BB * 3 * NN;
    int c = t & 31, og = t >> 5;
    for (int ss = 0; ss < 32; ss++) {
        int o = og * 32 + ss;
        o2[((size_t)(b * C2 + o)) * NN + n0 + c] = T[c][o];
    }
}

extern "C" void kernel_launch(void* const* d_in, const int* in_sizes, int n_in,
                              void* d_out, int out_size, void* d_ws, size_t ws_size,
                              hipStream_t stream) {
    const float* pos1 = (const float*)d_in[0];
    const float* pos2 = (const float*)d_in[1];
    const float* f1   = (const float*)d_in[2];
    const float* f2   = (const float*)d_in[3];
    const int*   idx  = (const int*)d_in[4];
    const float* W0 = (const float*)d_in[5];
    const float* g0 = (const float*)d_in[6];
    const float* b0 = (const float*)d_in[7];
    const float* W1 = (const float*)d_in[8];
    const float* g1 = (const float*)d_in[9];
    const float* b1 = (const float*)d_in[10];
    const float* W2 = (const float*)d_in[11];
    const float* g2 = (const float*)d_in[12];
    const float* b2 = (const float*)d_in[13];
    float* ws  = (float*)d_ws;
    float* out = (float*)d_out;
    ushort* wsu = (ushort*)d_ws;
    ushort* y0p = wsu + Y0_USH;
    ushort* T2p = wsu + T2_USH;
    ushort* T1p = wsu + T1_USH;
    short* wp0  = (short*)(wsu + WP_USH);

    // output 0: pos1 passthrough
    hipMemcpyAsync(d_out, d_in[0], (size_t)BB * 3 * NN * sizeof(float),
                   hipMemcpyDeviceToDevice, stream);

    prep<<<512 + 44, 256, 0, stream>>>(f2, pos2, f1, pos1, W0, W1, W2, T2p, T1p, wp0);

    pass_A<<<BB * NN / 4, 256, 0, stream>>>(T2p, T1p, idx, wp0, ws, y0p);
    reduce1<<<64, 256, 0, stream>>>(ws, PART, 32, 256, 256);
    finalize<<<1, 256, 0, stream>>>(g0, b0, ws, C0, PAR0);

    pass_B<<<BB * NN / 4, 256, 0, stream>>>(y0p, wp0, ws);
    reduce1<<<64, 256, 0, stream>>>(ws, PART, 128, 256, 256);
    finalize<<<1, 256, 0, stream>>>(g1, b1, ws, C0, PAR1);

    pass_C<<<BB * NN / 4, 256, 0, stream>>>(y0p, wp0, ws);
    reduce1<<<64, 256, 0, stream>>>(ws, PART, 32, 512, 512);
    finalize<<<1, 256, 0, stream>>>(g2, b2, ws, C2, PAR2);

    out_kernel<<<BB * (NN / 32), 256, 0, stream>>>(ws, out);
}